// Round 15
// baseline (400.412 us; speedup 1.0000x reference)
//
#include <hip/hip_runtime.h>
#include <stdint.h>

// GAT encoder: 3 GAT layers + masked global max pool.
// fp16-storage pipeline (threshold 2% relative; r14 absmax 9.8e-4).
// r15 agg: softmax without max-reduce (shift by wave-uniform leaky(ad) for
// f16 range safety), UNNORMALIZED half2(t,t)|col packed to LDS immediately
// (sum-reduce overlaps gather issue; Sinv applied once at the end), 16-deep
// gathers per half (single round for deg<=32), no predication in hot loop.

#define NN 20000
#define MPAD 20096
#define NE 320000
#define NBATCH 16
#define NEG 0.2f
#define WSCALE 64.0f
#define WINV 0.015625f

using f16x8 = __attribute__((ext_vector_type(8))) _Float16;
using f32x4 = __attribute__((ext_vector_type(4))) float;
using h2 = __attribute__((ext_vector_type(2))) _Float16;

#define GLL16(gp, lp)                                                        \
  __builtin_amdgcn_global_load_lds(                                          \
      (const __attribute__((address_space(1))) void*)(gp),                   \
      (__attribute__((address_space(3))) void*)(lp), 16, 0, 0)

static __device__ __forceinline__ unsigned short h2u(_Float16 h) {
  union { _Float16 f; unsigned short u; } c;
  c.f = h;
  return c.u;
}
static __device__ __forceinline__ h2 bits2h2(unsigned v) {
  union { unsigned u; h2 h; } c;
  c.u = v;
  return c.h;
}
static __device__ __forceinline__ unsigned h22bits(h2 h) {
  union { h2 h; unsigned u; } c;
  c.h = h;
  return c.u;
}
static __device__ __forceinline__ unsigned encf(float f) {
  unsigned u = __float_as_uint(f);
  return (u & 0x80000000u) ? ~u : (u | 0x80000000u);
}
static __device__ __forceinline__ float decf(unsigned u) {
  return __uint_as_float((u & 0x80000000u) ? (u ^ 0x80000000u) : ~u);
}

// ---------------- fused init: deg, enc, flag, alpha buffers ----------------
__global__ void k_init0(int* deg, unsigned* enc, int* flag, float* alz, int alcount) {
  int i = blockIdx.x * blockDim.x + threadIdx.x;
  if (i < NN) deg[i] = 1;  // self loop
  if (i < NBATCH * 128) enc[i] = ~__float_as_uint(-1e30f);  // encf(-1e30)
  if (i == 0) *flag = 0;
  for (int j = i; j < alcount; j += gridDim.x * blockDim.x) alz[j] = 0.f;
}

__global__ void k_count(const int* __restrict__ ei, int* __restrict__ deg) {
  int e = blockIdx.x * blockDim.x + threadIdx.x;
  if (e < NE) atomicAdd(&deg[ei[NE + e]], 1);
}

__global__ void k_scan(const int* __restrict__ deg, int* __restrict__ row_ptr,
                       int* __restrict__ cursor) {
  __shared__ int wsum[16];
  int t = threadIdx.x;  // 1024 threads
  int lane = t & 63, wid = t >> 6;
  const int CH = 20;
  int beg = t * CH;
  int s = 0;
  for (int i = 0; i < CH; i++) {
    int idx = beg + i;
    if (idx < NN) s += deg[idx];
  }
  int incl = s;
  for (int off = 1; off < 64; off <<= 1) {
    int v = __shfl_up(incl, off, 64);
    if (lane >= off) incl += v;
  }
  if (lane == 63) wsum[wid] = incl;
  __syncthreads();
  if (t < 16) {
    int v = wsum[t];
    int in2 = v;
    for (int off = 1; off < 16; off <<= 1) {
      int u = __shfl_up(in2, off, 16);
      if (t >= off) in2 += u;
    }
    wsum[t] = in2 - v;  // exclusive wave base
  }
  __syncthreads();
  int run = wsum[wid] + incl - s;
  for (int i = 0; i < CH; i++) {
    int idx = beg + i;
    if (idx < NN) {
      row_ptr[idx] = run;
      cursor[idx] = run;
      run += deg[idx];
    }
  }
  if (t == 1023) row_ptr[NN] = run;
}

__global__ void k_fill(const int* __restrict__ ei, int* __restrict__ cursor,
                       int* __restrict__ col, const int* __restrict__ nmask,
                       int* __restrict__ flag) {
  int i = blockIdx.x * blockDim.x + threadIdx.x;
  if (i >= NE + NN) return;
  int src, dst;
  if (i < NE) {
    src = ei[i];
    dst = ei[NE + i];
  } else {
    src = dst = i - NE;
    if (nmask[src] != 0) *flag = 1;
  }
  int pos = atomicAdd(&cursor[dst], 1);
  col[pos] = src;
}

// ---------------- fused prep: W1/W2/W3 transpose+scale+fp16, x->fp16 --------
#define R1 (512 * 128)
#define R2 (512 * 512)
#define R3 (128 * 512)
__global__ void k_prep(const float* __restrict__ W1, const float* __restrict__ W2,
                       const float* __restrict__ W3, const float* __restrict__ x,
                       unsigned short* __restrict__ wt1,
                       unsigned short* __restrict__ wt2,
                       unsigned short* __restrict__ wt3,
                       unsigned short* __restrict__ xp) {
  int idx = blockIdx.x * blockDim.x + threadIdx.x;
  if (idx < R1) {
    int n = idx & 511, k = idx >> 9;  // W1 [128][512]
    wt1[(size_t)n * 128 + k] = h2u((_Float16)(W1[(size_t)k * 512 + n] * WSCALE));
  } else if (idx < R1 + R2) {
    int j = idx - R1;
    int n = j & 511, k = j >> 9;  // W2 [512][512]
    wt2[(size_t)n * 512 + k] = h2u((_Float16)(W2[(size_t)k * 512 + n] * WSCALE));
  } else if (idx < R1 + R2 + R3) {
    int j = idx - (R1 + R2);
    int n = j & 127, k = j >> 7;  // W3 [512][128]
    wt3[(size_t)n * 512 + k] = h2u((_Float16)(W3[(size_t)k * 128 + n] * WSCALE));
  } else {
    int j = idx - (R1 + R2 + R3);
    if (j < NN * 128) xp[j] = h2u((_Float16)x[j]);
  }
}

// ---------------- GEMM: fp16 x fp16 -> fp16 C, fp32 acc, alpha fused --------
// Swapped mfma operands: thread (lquad,lrow) reg r holds C[m=lrow][n=lquad*4+r].
// Staging via global_load_lds width=16.
#define BN 128
#define BK 32

template <int BMT, int NT>
__global__ __launch_bounds__(NT, 3) void k_gemm(
    const unsigned short* __restrict__ Ap, const unsigned short* __restrict__ Wt,
    unsigned short* __restrict__ C, const float* __restrict__ attS,
    const float* __restrict__ attD, float* __restrict__ alS,
    float* __restrict__ alD, int K, int Nc, int H) {
  __shared__ __align__(16) unsigned short As[BMT][BK];
  __shared__ __align__(16) unsigned short Bs[BN][BK];
  int tid = threadIdx.x;
  int bm = blockIdx.y * BMT, bn = blockIdx.x * BN;
  int wid = tid >> 6, lane = tid & 63;
  int wm = (BMT == 128) ? (wid >> 1) * 64 : 0;
  int wn = (BMT == 128) ? (wid & 1) * 64 : wid * 64;
  int lrow = lane & 15, lquad = lane >> 4;

  f32x4 acc[4][4] = {};

  for (int k0 = 0; k0 < K; k0 += BK) {
    __syncthreads();
#pragma unroll
    for (int i = 0; i < (BMT * 4) / NT; i++) {
      int slot = tid + NT * i;
      int row = slot >> 2;
      int ks = (slot & 3) * 8;
      GLL16(Ap + (size_t)(bm + row) * K + k0 + ks, &As[0][0] + (size_t)slot * 8);
    }
#pragma unroll
    for (int i = 0; i < 512 / NT; i++) {
      int slot = tid + NT * i;
      int row = slot >> 2;
      int ks = (slot & 3) * 8;
      GLL16(Wt + (size_t)(bn + row) * K + k0 + ks, &Bs[0][0] + (size_t)slot * 8);
    }
    __syncthreads();

    f16x8 af[4];
#pragma unroll
    for (int mf = 0; mf < 4; mf++)
      af[mf] = *(const f16x8*)&As[wm + mf * 16 + lrow][lquad * 8];
#pragma unroll
    for (int nf = 0; nf < 4; nf++) {
      f16x8 bf = *(const f16x8*)&Bs[wn + nf * 16 + lrow][lquad * 8];
#pragma unroll
      for (int mf = 0; mf < 4; mf++)
        acc[mf][nf] =
            __builtin_amdgcn_mfma_f32_16x16x32_f16(bf, af[mf], acc[mf][nf], 0, 0, 0);
    }
  }
  // undo the x64 W scale
#pragma unroll
  for (int mf = 0; mf < 4; mf++)
#pragma unroll
    for (int nf = 0; nf < 4; nf++)
#pragma unroll
      for (int r = 0; r < 4; r++) acc[mf][nf][r] *= WINV;

  // fused alpha (this block's 128 cols == one head)
  float4 aS[4], aD[4];
#pragma unroll
  for (int nf = 0; nf < 4; nf++) {
    int n0 = bn + wn + nf * 16 + lquad * 4;
    aS[nf] = *(const float4*)(attS + n0);
    aD[nf] = *(const float4*)(attD + n0);
  }
  int head = bn >> 7;
#pragma unroll
  for (int mf = 0; mf < 4; mf++) {
    float ps = 0.f, pd = 0.f;
#pragma unroll
    for (int nf = 0; nf < 4; nf++) {
      ps += acc[mf][nf][0] * aS[nf].x + acc[mf][nf][1] * aS[nf].y +
            acc[mf][nf][2] * aS[nf].z + acc[mf][nf][3] * aS[nf].w;
      pd += acc[mf][nf][0] * aD[nf].x + acc[mf][nf][1] * aD[nf].y +
            acc[mf][nf][2] * aD[nf].z + acc[mf][nf][3] * aD[nf].w;
    }
    ps += __shfl_xor(ps, 16, 64);
    ps += __shfl_xor(ps, 32, 64);
    pd += __shfl_xor(pd, 16, 64);
    pd += __shfl_xor(pd, 32, 64);
    int row = bm + wm + mf * 16 + lrow;
    if (lquad == 0) {
      atomicAdd(&alS[(size_t)row * H + head], ps);
      atomicAdd(&alD[(size_t)row * H + head], pd);
    }
  }
  // C store: one 8B ushort4 per (mf,nf)
#pragma unroll
  for (int mf = 0; mf < 4; mf++) {
    int m = bm + wm + mf * 16 + lrow;
#pragma unroll
    for (int nf = 0; nf < 4; nf++) {
      int n0 = bn + wn + nf * 16 + lquad * 4;
      ushort4 o;
      o.x = h2u((_Float16)acc[mf][nf][0]);
      o.y = h2u((_Float16)acc[mf][nf][1]);
      o.z = h2u((_Float16)acc[mf][nf][2]);
      o.w = h2u((_Float16)acc[mf][nf][3]);
      *(ushort4*)(C + (size_t)m * Nc + n0) = o;
    }
  }
}

// ---------------- softmax + aggregate: 1 head/wave, half-wave edge pairs ----
// PIN=true (H=4): sub = blockIdx&3 -> head s on XCDs {s, s+4}.
// Fast path (deg<=64): t = exp(leaky(e) - leaky(adv)) packed UNNORMALIZED to
// LDS immediately (no max-reduce; sum-reduce overlaps gather issue); final
// scale by Sinv after the half merge. 16 gathers per half in flight.
template <int H, bool RELU, bool FP16OUT, bool PIN>
__global__ __launch_bounds__(256) void k_agg(
    const unsigned short* __restrict__ h, const float* __restrict__ as_,
    const float* __restrict__ ad_, const int* __restrict__ row_ptr,
    const int* __restrict__ col, const float* __restrict__ bias,
    float* __restrict__ out, unsigned short* __restrict__ outp) {
  constexpr int HF = H * 128;
  __shared__ unsigned long long cw[4][64];
  int tid = threadIdx.x, bwid = tid >> 6, lane = tid & 63;
  int node, sub;
  if constexpr (PIN) {
    sub = blockIdx.x & 3;
    node = (blockIdx.x >> 2) * 4 + bwid;  // grid = NN, NN%4==0
  } else {
    node = blockIdx.x * 4 + bwid;
    sub = 0;
    if (node >= NN) return;
  }
  int beg = row_ptr[node], end = row_ptr[node + 1];
  int deg = end - beg;
  float adv = ad_[(size_t)node * H + sub];
  float shift = (adv > 0.f) ? adv : NEG * adv;  // wave-uniform surrogate max
  float fscale = 1.f;
  bool fast = (deg <= 64);

  if (__builtin_expect(fast, 1)) {
    unsigned sidx = 0;
    float t = 0.f;
    if (lane < deg) {
      sidx = (unsigned)col[beg + lane];
      float e = as_[(size_t)sidx * H + sub] + adv;
      e = (e > 0.f) ? e : NEG * e;
      t = __expf(e - shift);
    }
    _Float16 ht = (_Float16)t;
    h2 hv;
    hv[0] = ht;
    hv[1] = ht;
    cw[bwid][lane] = ((unsigned long long)h22bits(hv) << 32) | sidx;
    float S = t;  // sum reduce; overlaps with phase-B gather issue
#pragma unroll
    for (int off = 32; off; off >>= 1) S += __shfl_xor(S, off, 64);
    fscale = 1.f / S;
  }
  float Mr = 0.f, Sinv = 0.f;
  if (!fast) {  // rare general path: normalized weights per chunk
    float m = -1e30f, s = 0.f;
    for (int j = beg + lane; j < end; j += 64) {
      int sidx = col[j];
      float e = as_[(size_t)sidx * H + sub] + adv;
      e = (e > 0.f) ? e : NEG * e;
      float nm = fmaxf(m, e);
      s = s * __expf(m - nm) + __expf(e - nm);
      m = nm;
    }
    float mm = m;
#pragma unroll
    for (int off = 32; off; off >>= 1) mm = fmaxf(mm, __shfl_xor(mm, off, 64));
    float t = s * __expf(m - mm);
#pragma unroll
    for (int off = 32; off; off >>= 1) t += __shfl_xor(t, off, 64);
    Mr = mm;
    Sinv = 1.f / t;
  }

  const int half = lane >> 5, hl = lane & 31;
  const int fbase = sub * 128 + hl * 4;  // 4 features/lane, 32 lanes = head row
  const int base = half * 16;
  float acc0 = 0.f, acc1 = 0.f, acc2 = 0.f, acc3 = 0.f;
  for (int c0 = beg; c0 < end; c0 += 64) {
    int cnt = min(64, end - c0);
    if (!fast) {  // refill normalized weights; zero-pad all 64 slots
      unsigned sidx = 0;
      float w = 0.f;
      if (lane < cnt) {
        sidx = (unsigned)col[c0 + lane];
        float e = as_[(size_t)sidx * H + sub] + adv;
        e = (e > 0.f) ? e : NEG * e;
        w = __expf(e - Mr) * Sinv;
      }
      _Float16 hw = (_Float16)w;
      h2 hv;
      hv[0] = hw;
      hv[1] = hw;
      cw[bwid][lane] = ((unsigned long long)h22bits(hv) << 32) | sidx;
    }
    h2 hacc0 = {(_Float16)0.f, (_Float16)0.f};
    h2 hacc1 = {(_Float16)0.f, (_Float16)0.f};
    for (int je = 0; je < cnt; je += 32) {  // 32 edges/round (16 per half)
      unsigned long long q[16];
#pragma unroll
      for (int r = 0; r < 16; r++) q[r] = cw[bwid][je + base + r];
      uint2 v[16];
#pragma unroll
      for (int r = 0; r < 16; r++)
        v[r] = *(const uint2*)(h + (size_t)(unsigned)q[r] * HF + fbase);
#pragma unroll
      for (int r = 0; r < 16; r++) {
        h2 hw = bits2h2((unsigned)(q[r] >> 32));
        hacc0 += hw * bits2h2(v[r].x);
        hacc1 += hw * bits2h2(v[r].y);
      }
    }
    acc0 += (float)hacc0[0];
    acc1 += (float)hacc0[1];
    acc2 += (float)hacc1[0];
    acc3 += (float)hacc1[1];
  }
  // merge the two halves, then normalize (fast path) or pass through (slow)
  acc0 += __shfl_xor(acc0, 32, 64);
  acc1 += __shfl_xor(acc1, 32, 64);
  acc2 += __shfl_xor(acc2, 32, 64);
  acc3 += __shfl_xor(acc3, 32, 64);
  if (half == 0) {
    float4 b = *(const float4*)(bias + fbase);
    float v0 = acc0 * fscale + b.x, v1 = acc1 * fscale + b.y;
    float v2 = acc2 * fscale + b.z, v3 = acc3 * fscale + b.w;
    if (RELU) {
      v0 = fmaxf(v0, 0.f);
      v1 = fmaxf(v1, 0.f);
      v2 = fmaxf(v2, 0.f);
      v3 = fmaxf(v3, 0.f);
    }
    if constexpr (FP16OUT) {
      ushort4 o;
      o.x = h2u((_Float16)v0);
      o.y = h2u((_Float16)v1);
      o.z = h2u((_Float16)v2);
      o.w = h2u((_Float16)v3);
      *(ushort4*)(outp + (size_t)node * HF + fbase) = o;
    } else {
      float4 o = make_float4(v0, v1, v2, v3);
      *(float4*)(out + (size_t)node * HF + fbase) = o;
    }
  }
}

// ---------------- masked global max pool ----------------
__global__ void k_pool(const float* __restrict__ h, const int* __restrict__ batch,
                       const int* __restrict__ mask, const int* __restrict__ flag,
                       unsigned* __restrict__ enc) {
  int f = threadIdx.x;  // 128 threads = 128 features
  int n0 = blockIdx.x * 32;
  if (n0 >= NN) return;
  int n1 = min(NN, n0 + 32);
  int any = *flag;
  float local = -1e30f;
  int curb = batch[n0];
  for (int n = n0; n < n1; ++n) {
    int b = batch[n];
    if (b != curb) {
      if (local > -1e30f) atomicMax(&enc[curb * 128 + f], encf(local));
      local = -1e30f;
      curb = b;
    }
    bool valid = (mask[n] == 0) || (!any);
    if (valid) local = fmaxf(local, h[(size_t)n * 128 + f]);
  }
  if (local > -1e30f) atomicMax(&enc[curb * 128 + f], encf(local));
}

__global__ void k_out(const unsigned* __restrict__ enc, float* __restrict__ out) {
  int i = blockIdx.x * blockDim.x + threadIdx.x;
  if (i < NBATCH * 128) out[i] = decf(enc[i]);
}

extern "C" void kernel_launch(void* const* d_in, const int* in_sizes, int n_in,
                              void* d_out, int out_size, void* d_ws, size_t ws_size,
                              hipStream_t stream) {
  const float* x = (const float*)d_in[0];
  const int* ei = (const int*)d_in[1];
  const int* batch = (const int*)d_in[2];
  const int* nmask = (const int*)d_in[3];
  // d_in[4] = edge_mask, unused
  const float* W1 = (const float*)d_in[5];
  const float* as1 = (const float*)d_in[6];
  const float* ad1 = (const float*)d_in[7];
  const float* b1 = (const float*)d_in[8];
  const float* W2 = (const float*)d_in[9];
  const float* as2 = (const float*)d_in[10];
  const float* ad2 = (const float*)d_in[11];
  const float* b2 = (const float*)d_in[12];
  const float* W3 = (const float*)d_in[13];
  const float* as3 = (const float*)d_in[14];
  const float* ad3 = (const float*)d_in[15];
  const float* b3 = (const float*)d_in[16];

  char* ws = (char*)d_ws;
  size_t off = 0;
  auto alloc = [&](size_t bytes) -> char* {
    char* p = ws + off;
    off = (off + bytes + 255) & ~(size_t)255;
    return p;
  };
  unsigned short* hA = (unsigned short*)alloc((size_t)MPAD * 512 * 2);  // 20.6 MB
  unsigned short* hG = (unsigned short*)alloc((size_t)MPAD * 512 * 2);  // 20.6 MB
  float* out3 = (float*)alloc((size_t)MPAD * 128 * 4);                  // 10.3 MB
  unsigned short* xP = (unsigned short*)out3;  // alias: xP dead before out3 written
  unsigned short* wt1 = (unsigned short*)alloc((size_t)512 * 128 * 2);
  unsigned short* wt2 = (unsigned short*)alloc((size_t)512 * 512 * 2);
  unsigned short* wt3 = (unsigned short*)alloc((size_t)128 * 512 * 2);
  char* alStart = ws + off;
  float* alS1 = (float*)alloc((size_t)MPAD * 4 * 4);
  float* alD1 = (float*)alloc((size_t)MPAD * 4 * 4);
  float* alS2 = (float*)alloc((size_t)MPAD * 4 * 4);
  float* alD2 = (float*)alloc((size_t)MPAD * 4 * 4);
  float* alS3 = (float*)alloc((size_t)MPAD * 4);
  float* alD3 = (float*)alloc((size_t)MPAD * 4);
  int alcount = (int)(((ws + off) - alStart) / 4);
  int* deg = (int*)alloc((size_t)NN * 4);
  int* cursor = (int*)alloc((size_t)NN * 4);
  int* rowp = (int*)alloc((size_t)(NN + 1) * 4);
  int* colx = (int*)alloc((size_t)(NE + NN) * 4);
  unsigned* enc = (unsigned*)alloc((size_t)NBATCH * 128 * 4);
  int* flag = (int*)alloc(4);
  (void)ws_size; (void)n_in; (void)in_sizes; (void)out_size;

  k_init0<<<(alcount + 255) / 256, 256, 0, stream>>>((int*)deg, enc, flag,
                                                     (float*)alStart, alcount);
  k_count<<<(NE + 255) / 256, 256, 0, stream>>>(ei, deg);
  k_scan<<<1, 1024, 0, stream>>>(deg, rowp, cursor);
  k_fill<<<(NE + NN + 255) / 256, 256, 0, stream>>>(ei, cursor, colx, nmask, flag);
  {
    int total = R1 + R2 + R3 + NN * 128;
    k_prep<<<(total + 255) / 256, 256, 0, stream>>>(W1, W2, W3, x, wt1, wt2, wt3, xP);
  }

  dim3 gg1(512 / BN, MPAD / 128);
  dim3 gg3(1, MPAD / 64);

  // Layer 1
  k_gemm<128, 256><<<gg1, 256, 0, stream>>>(xP, wt1, hA, as1, ad1, alS1, alD1,
                                            128, 512, 4);
  k_agg<4, true, true, true><<<NN, 256, 0, stream>>>(hA, alS1, alD1, rowp, colx,
                                                     b1, nullptr, hG);
  // Layer 2
  k_gemm<128, 256><<<gg1, 256, 0, stream>>>(hG, wt2, hA, as2, ad2, alS2, alD2,
                                            512, 512, 4);
  k_agg<4, true, true, true><<<NN, 256, 0, stream>>>(hA, alS2, alD2, rowp, colx,
                                                     b2, nullptr, hG);
  // Layer 3
  k_gemm<64, 128><<<gg3, 128, 0, stream>>>(hG, wt3, hA, as3, ad3, alS3, alD3,
                                           512, 128, 1);
  k_agg<1, false, false, false><<<(NN + 3) / 4, 256, 0, stream>>>(
      hA, alS3, alD3, rowp, colx, b3, out3, nullptr);

  // Masked global max pool
  k_pool<<<(NN + 31) / 32, 128, 0, stream>>>(out3, batch, nmask, flag, enc);
  k_out<<<(NBATCH * 128 + 255) / 256, 256, 0, stream>>>(enc, (float*)d_out);
}

// Round 16
// 348.196 us; speedup vs baseline: 1.1500x; 1.1500x over previous
//
#include <hip/hip_runtime.h>
#include <stdint.h>

// GAT encoder: 3 GAT layers + masked global max pool.
// fp16-storage pipeline (threshold 2% relative; r14 absmax 9.8e-4).
// r16 = r14 agg (8-deep, pk_fma, VGPR~36) + softmax-chain cut (no max-reduce,
// deferred normalization; validated numerically in r15) + merged init/prep.

#define NN 20000
#define MPAD 20096
#define NE 320000
#define NBATCH 16
#define NEG 0.2f
#define WSCALE 64.0f
#define WINV 0.015625f

using f16x8 = __attribute__((ext_vector_type(8))) _Float16;
using f32x4 = __attribute__((ext_vector_type(4))) float;
using h2 = __attribute__((ext_vector_type(2))) _Float16;

#define GLL16(gp, lp)                                                        \
  __builtin_amdgcn_global_load_lds(                                          \
      (const __attribute__((address_space(1))) void*)(gp),                   \
      (__attribute__((address_space(3))) void*)(lp), 16, 0, 0)

static __device__ __forceinline__ unsigned short h2u(_Float16 h) {
  union { _Float16 f; unsigned short u; } c;
  c.f = h;
  return c.u;
}
static __device__ __forceinline__ h2 bits2h2(unsigned v) {
  union { unsigned u; h2 h; } c;
  c.u = v;
  return c.h;
}
static __device__ __forceinline__ unsigned h22bits(h2 h) {
  union { h2 h; unsigned u; } c;
  c.h = h;
  return c.u;
}
static __device__ __forceinline__ unsigned encf(float f) {
  unsigned u = __float_as_uint(f);
  return (u & 0x80000000u) ? ~u : (u | 0x80000000u);
}
static __device__ __forceinline__ float decf(unsigned u) {
  return __uint_as_float((u & 0x80000000u) ? (u ^ 0x80000000u) : ~u);
}

// -------- fused init+prep: deg/enc/flag/alpha-zero + W->fp16^T + x->fp16 ----
#define R1 (512 * 128)
#define R2 (512 * 512)
#define R3 (128 * 512)
#define PREPTOT (R1 + R2 + R3 + NN * 128)
__global__ void k_init_prep(const float* __restrict__ W1, const float* __restrict__ W2,
                            const float* __restrict__ W3, const float* __restrict__ x,
                            unsigned short* __restrict__ wt1,
                            unsigned short* __restrict__ wt2,
                            unsigned short* __restrict__ wt3,
                            unsigned short* __restrict__ xp, int* deg,
                            unsigned* enc, int* flag, float* alz, int alcount) {
  int idx = blockIdx.x * blockDim.x + threadIdx.x;
  if (idx < R1) {
    int n = idx & 511, k = idx >> 9;  // W1 [128][512]
    wt1[(size_t)n * 128 + k] = h2u((_Float16)(W1[(size_t)k * 512 + n] * WSCALE));
  } else if (idx < R1 + R2) {
    int j = idx - R1;
    int n = j & 511, k = j >> 9;  // W2 [512][512]
    wt2[(size_t)n * 512 + k] = h2u((_Float16)(W2[(size_t)k * 512 + n] * WSCALE));
  } else if (idx < R1 + R2 + R3) {
    int j = idx - (R1 + R2);
    int n = j & 127, k = j >> 7;  // W3 [512][128]
    wt3[(size_t)n * 512 + k] = h2u((_Float16)(W3[(size_t)k * 128 + n] * WSCALE));
  } else if (idx < PREPTOT) {
    int j = idx - (R1 + R2 + R3);
    xp[j] = h2u((_Float16)x[j]);
  }
  if (idx < NN) deg[idx] = 1;  // self loop
  if (idx < NBATCH * 128) enc[idx] = ~__float_as_uint(-1e30f);  // encf(-1e30)
  if (idx == 0) *flag = 0;
  if (idx < alcount) alz[idx] = 0.f;
}

__global__ void k_count(const int* __restrict__ ei, int* __restrict__ deg) {
  int e = blockIdx.x * blockDim.x + threadIdx.x;
  if (e < NE) atomicAdd(&deg[ei[NE + e]], 1);
}

__global__ void k_scan(const int* __restrict__ deg, int* __restrict__ row_ptr,
                       int* __restrict__ cursor) {
  __shared__ int wsum[16];
  int t = threadIdx.x;  // 1024 threads
  int lane = t & 63, wid = t >> 6;
  const int CH = 20;
  int beg = t * CH;
  int s = 0;
  for (int i = 0; i < CH; i++) {
    int idx = beg + i;
    if (idx < NN) s += deg[idx];
  }
  int incl = s;
  for (int off = 1; off < 64; off <<= 1) {
    int v = __shfl_up(incl, off, 64);
    if (lane >= off) incl += v;
  }
  if (lane == 63) wsum[wid] = incl;
  __syncthreads();
  if (t < 16) {
    int v = wsum[t];
    int in2 = v;
    for (int off = 1; off < 16; off <<= 1) {
      int u = __shfl_up(in2, off, 16);
      if (t >= off) in2 += u;
    }
    wsum[t] = in2 - v;  // exclusive wave base
  }
  __syncthreads();
  int run = wsum[wid] + incl - s;
  for (int i = 0; i < CH; i++) {
    int idx = beg + i;
    if (idx < NN) {
      row_ptr[idx] = run;
      cursor[idx] = run;
      run += deg[idx];
    }
  }
  if (t == 1023) row_ptr[NN] = run;
}

__global__ void k_fill(const int* __restrict__ ei, int* __restrict__ cursor,
                       int* __restrict__ col, const int* __restrict__ nmask,
                       int* __restrict__ flag) {
  int i = blockIdx.x * blockDim.x + threadIdx.x;
  if (i >= NE + NN) return;
  int src, dst;
  if (i < NE) {
    src = ei[i];
    dst = ei[NE + i];
  } else {
    src = dst = i - NE;
    if (nmask[src] != 0) *flag = 1;
  }
  int pos = atomicAdd(&cursor[dst], 1);
  col[pos] = src;
}

// ---------------- GEMM: fp16 x fp16 -> fp16 C, fp32 acc, alpha fused --------
// Swapped mfma operands: thread (lquad,lrow) reg r holds C[m=lrow][n=lquad*4+r].
// Staging via global_load_lds width=16.
#define BN 128
#define BK 32

template <int BMT, int NT>
__global__ __launch_bounds__(NT, 3) void k_gemm(
    const unsigned short* __restrict__ Ap, const unsigned short* __restrict__ Wt,
    unsigned short* __restrict__ C, const float* __restrict__ attS,
    const float* __restrict__ attD, float* __restrict__ alS,
    float* __restrict__ alD, int K, int Nc, int H) {
  __shared__ __align__(16) unsigned short As[BMT][BK];
  __shared__ __align__(16) unsigned short Bs[BN][BK];
  int tid = threadIdx.x;
  int bm = blockIdx.y * BMT, bn = blockIdx.x * BN;
  int wid = tid >> 6, lane = tid & 63;
  int wm = (BMT == 128) ? (wid >> 1) * 64 : 0;
  int wn = (BMT == 128) ? (wid & 1) * 64 : wid * 64;
  int lrow = lane & 15, lquad = lane >> 4;

  f32x4 acc[4][4] = {};

  for (int k0 = 0; k0 < K; k0 += BK) {
    __syncthreads();
#pragma unroll
    for (int i = 0; i < (BMT * 4) / NT; i++) {
      int slot = tid + NT * i;
      int row = slot >> 2;
      int ks = (slot & 3) * 8;
      GLL16(Ap + (size_t)(bm + row) * K + k0 + ks, &As[0][0] + (size_t)slot * 8);
    }
#pragma unroll
    for (int i = 0; i < 512 / NT; i++) {
      int slot = tid + NT * i;
      int row = slot >> 2;
      int ks = (slot & 3) * 8;
      GLL16(Wt + (size_t)(bn + row) * K + k0 + ks, &Bs[0][0] + (size_t)slot * 8);
    }
    __syncthreads();

    f16x8 af[4];
#pragma unroll
    for (int mf = 0; mf < 4; mf++)
      af[mf] = *(const f16x8*)&As[wm + mf * 16 + lrow][lquad * 8];
#pragma unroll
    for (int nf = 0; nf < 4; nf++) {
      f16x8 bf = *(const f16x8*)&Bs[wn + nf * 16 + lrow][lquad * 8];
#pragma unroll
      for (int mf = 0; mf < 4; mf++)
        acc[mf][nf] =
            __builtin_amdgcn_mfma_f32_16x16x32_f16(bf, af[mf], acc[mf][nf], 0, 0, 0);
    }
  }
  // undo the x64 W scale
#pragma unroll
  for (int mf = 0; mf < 4; mf++)
#pragma unroll
    for (int nf = 0; nf < 4; nf++)
#pragma unroll
      for (int r = 0; r < 4; r++) acc[mf][nf][r] *= WINV;

  // fused alpha (this block's 128 cols == one head)
  float4 aS[4], aD[4];
#pragma unroll
  for (int nf = 0; nf < 4; nf++) {
    int n0 = bn + wn + nf * 16 + lquad * 4;
    aS[nf] = *(const float4*)(attS + n0);
    aD[nf] = *(const float4*)(attD + n0);
  }
  int head = bn >> 7;
#pragma unroll
  for (int mf = 0; mf < 4; mf++) {
    float ps = 0.f, pd = 0.f;
#pragma unroll
    for (int nf = 0; nf < 4; nf++) {
      ps += acc[mf][nf][0] * aS[nf].x + acc[mf][nf][1] * aS[nf].y +
            acc[mf][nf][2] * aS[nf].z + acc[mf][nf][3] * aS[nf].w;
      pd += acc[mf][nf][0] * aD[nf].x + acc[mf][nf][1] * aD[nf].y +
            acc[mf][nf][2] * aD[nf].z + acc[mf][nf][3] * aD[nf].w;
    }
    ps += __shfl_xor(ps, 16, 64);
    ps += __shfl_xor(ps, 32, 64);
    pd += __shfl_xor(pd, 16, 64);
    pd += __shfl_xor(pd, 32, 64);
    int row = bm + wm + mf * 16 + lrow;
    if (lquad == 0) {
      atomicAdd(&alS[(size_t)row * H + head], ps);
      atomicAdd(&alD[(size_t)row * H + head], pd);
    }
  }
  // C store: one 8B ushort4 per (mf,nf)
#pragma unroll
  for (int mf = 0; mf < 4; mf++) {
    int m = bm + wm + mf * 16 + lrow;
#pragma unroll
    for (int nf = 0; nf < 4; nf++) {
      int n0 = bn + wn + nf * 16 + lquad * 4;
      ushort4 o;
      o.x = h2u((_Float16)acc[mf][nf][0]);
      o.y = h2u((_Float16)acc[mf][nf][1]);
      o.z = h2u((_Float16)acc[mf][nf][2]);
      o.w = h2u((_Float16)acc[mf][nf][3]);
      *(ushort4*)(C + (size_t)m * Nc + n0) = o;
    }
  }
}

// ---------------- softmax + aggregate: 1 head/wave, half-wave edge pairs ----
// PIN=true (H=4): sub = blockIdx&3 -> head s on XCDs {s, s+4}.
// Fast path (deg<=64): t = exp(leaky(e) - leaky(adv)) packed UNNORMALIZED to
// LDS immediately (no max-reduce; sum-reduce overlaps gather issue); final
// scale by 1/S after the half merge. 8 gathers per half in flight (r14 shape,
// VGPR ~36 -- r15's 16-deep variant blew occupancy).
template <int H, bool RELU, bool FP16OUT, bool PIN>
__global__ __launch_bounds__(256) void k_agg(
    const unsigned short* __restrict__ h, const float* __restrict__ as_,
    const float* __restrict__ ad_, const int* __restrict__ row_ptr,
    const int* __restrict__ col, const float* __restrict__ bias,
    float* __restrict__ out, unsigned short* __restrict__ outp) {
  constexpr int HF = H * 128;
  __shared__ unsigned long long cw[4][64];
  int tid = threadIdx.x, bwid = tid >> 6, lane = tid & 63;
  int node, sub;
  if constexpr (PIN) {
    sub = blockIdx.x & 3;
    node = (blockIdx.x >> 2) * 4 + bwid;  // grid = NN, NN%4==0
  } else {
    node = blockIdx.x * 4 + bwid;
    sub = 0;
    if (node >= NN) return;
  }
  int beg = row_ptr[node], end = row_ptr[node + 1];
  int deg = end - beg;
  float adv = ad_[(size_t)node * H + sub];
  float shift = (adv > 0.f) ? adv : NEG * adv;  // wave-uniform surrogate max
  float fscale = 1.f;
  bool fast = (deg <= 64);

  if (__builtin_expect(fast, 1)) {
    unsigned sidx = 0;
    float t = 0.f;
    if (lane < deg) {
      sidx = (unsigned)col[beg + lane];
      float e = as_[(size_t)sidx * H + sub] + adv;
      e = (e > 0.f) ? e : NEG * e;
      t = fminf(__expf(e - shift), 60000.f);  // f16-range guard
    }
    _Float16 ht = (_Float16)t;
    h2 hv;
    hv[0] = ht;
    hv[1] = ht;
    cw[bwid][lane] = ((unsigned long long)h22bits(hv) << 32) | sidx;
    float S = t;  // sum reduce; overlaps with phase-B gather issue
#pragma unroll
    for (int off = 32; off; off >>= 1) S += __shfl_xor(S, off, 64);
    fscale = 1.f / S;
  }
  float Mr = 0.f, Sinv = 0.f;
  if (!fast) {  // rare general path: normalized weights per chunk
    float m = -1e30f, s = 0.f;
    for (int j = beg + lane; j < end; j += 64) {
      int sidx = col[j];
      float e = as_[(size_t)sidx * H + sub] + adv;
      e = (e > 0.f) ? e : NEG * e;
      float nm = fmaxf(m, e);
      s = s * __expf(m - nm) + __expf(e - nm);
      m = nm;
    }
    float mm = m;
#pragma unroll
    for (int off = 32; off; off >>= 1) mm = fmaxf(mm, __shfl_xor(mm, off, 64));
    float t = s * __expf(m - mm);
#pragma unroll
    for (int off = 32; off; off >>= 1) t += __shfl_xor(t, off, 64);
    Mr = mm;
    Sinv = 1.f / t;
  }

  const int half = lane >> 5, hl = lane & 31;
  const int fbase = sub * 128 + hl * 4;  // 4 features/lane, 32 lanes = head row
  const int base = half * 8;
  float acc0 = 0.f, acc1 = 0.f, acc2 = 0.f, acc3 = 0.f;
  for (int c0 = beg; c0 < end; c0 += 64) {
    int cnt = min(64, end - c0);
    if (!fast) {  // refill normalized weights; zero-pad all 64 slots
      unsigned sidx = 0;
      float w = 0.f;
      if (lane < cnt) {
        sidx = (unsigned)col[c0 + lane];
        float e = as_[(size_t)sidx * H + sub] + adv;
        e = (e > 0.f) ? e : NEG * e;
        w = __expf(e - Mr) * Sinv;
      }
      _Float16 hw = (_Float16)w;
      h2 hv;
      hv[0] = hw;
      hv[1] = hw;
      cw[bwid][lane] = ((unsigned long long)h22bits(hv) << 32) | sidx;
    }
    h2 hacc0 = {(_Float16)0.f, (_Float16)0.f};
    h2 hacc1 = {(_Float16)0.f, (_Float16)0.f};
    for (int je = 0; je < cnt; je += 16) {  // 16 edges/iter (8 per half)
      unsigned long long q[8];
#pragma unroll
      for (int r = 0; r < 8; r++) q[r] = cw[bwid][je + base + r];
      uint2 v[8];
#pragma unroll
      for (int r = 0; r < 8; r++)
        v[r] = *(const uint2*)(h + (size_t)(unsigned)q[r] * HF + fbase);
#pragma unroll
      for (int r = 0; r < 8; r++) {
        h2 hw = bits2h2((unsigned)(q[r] >> 32));
        hacc0 += hw * bits2h2(v[r].x);
        hacc1 += hw * bits2h2(v[r].y);
      }
    }
    acc0 += (float)hacc0[0];
    acc1 += (float)hacc0[1];
    acc2 += (float)hacc1[0];
    acc3 += (float)hacc1[1];
  }
  // merge the two halves, then apply deferred normalization
  acc0 += __shfl_xor(acc0, 32, 64);
  acc1 += __shfl_xor(acc1, 32, 64);
  acc2 += __shfl_xor(acc2, 32, 64);
  acc3 += __shfl_xor(acc3, 32, 64);
  if (half == 0) {
    float4 b = *(const float4*)(bias + fbase);
    float v0 = acc0 * fscale + b.x, v1 = acc1 * fscale + b.y;
    float v2 = acc2 * fscale + b.z, v3 = acc3 * fscale + b.w;
    if (RELU) {
      v0 = fmaxf(v0, 0.f);
      v1 = fmaxf(v1, 0.f);
      v2 = fmaxf(v2, 0.f);
      v3 = fmaxf(v3, 0.f);
    }
    if constexpr (FP16OUT) {
      ushort4 o;
      o.x = h2u((_Float16)v0);
      o.y = h2u((_Float16)v1);
      o.z = h2u((_Float16)v2);
      o.w = h2u((_Float16)v3);
      *(ushort4*)(outp + (size_t)node * HF + fbase) = o;
    } else {
      float4 o = make_float4(v0, v1, v2, v3);
      *(float4*)(out + (size_t)node * HF + fbase) = o;
    }
  }
}

// ---------------- masked global max pool ----------------
__global__ void k_pool(const float* __restrict__ h, const int* __restrict__ batch,
                       const int* __restrict__ mask, const int* __restrict__ flag,
                       unsigned* __restrict__ enc) {
  int f = threadIdx.x;  // 128 threads = 128 features
  int n0 = blockIdx.x * 32;
  if (n0 >= NN) return;
  int n1 = min(NN, n0 + 32);
  int any = *flag;
  float local = -1e30f;
  int curb = batch[n0];
  for (int n = n0; n < n1; ++n) {
    int b = batch[n];
    if (b != curb) {
      if (local > -1e30f) atomicMax(&enc[curb * 128 + f], encf(local));
      local = -1e30f;
      curb = b;
    }
    bool valid = (mask[n] == 0) || (!any);
    if (valid) local = fmaxf(local, h[(size_t)n * 128 + f]);
  }
  if (local > -1e30f) atomicMax(&enc[curb * 128 + f], encf(local));
}

__global__ void k_out(const unsigned* __restrict__ enc, float* __restrict__ out) {
  int i = blockIdx.x * blockDim.x + threadIdx.x;
  if (i < NBATCH * 128) out[i] = decf(enc[i]);
}

extern "C" void kernel_launch(void* const* d_in, const int* in_sizes, int n_in,
                              void* d_out, int out_size, void* d_ws, size_t ws_size,
                              hipStream_t stream) {
  const float* x = (const float*)d_in[0];
  const int* ei = (const int*)d_in[1];
  const int* batch = (const int*)d_in[2];
  const int* nmask = (const int*)d_in[3];
  // d_in[4] = edge_mask, unused
  const float* W1 = (const float*)d_in[5];
  const float* as1 = (const float*)d_in[6];
  const float* ad1 = (const float*)d_in[7];
  const float* b1 = (const float*)d_in[8];
  const float* W2 = (const float*)d_in[9];
  const float* as2 = (const float*)d_in[10];
  const float* ad2 = (const float*)d_in[11];
  const float* b2 = (const float*)d_in[12];
  const float* W3 = (const float*)d_in[13];
  const float* as3 = (const float*)d_in[14];
  const float* ad3 = (const float*)d_in[15];
  const float* b3 = (const float*)d_in[16];

  char* ws = (char*)d_ws;
  size_t off = 0;
  auto alloc = [&](size_t bytes) -> char* {
    char* p = ws + off;
    off = (off + bytes + 255) & ~(size_t)255;
    return p;
  };
  unsigned short* hA = (unsigned short*)alloc((size_t)MPAD * 512 * 2);  // 20.6 MB
  unsigned short* hG = (unsigned short*)alloc((size_t)MPAD * 512 * 2);  // 20.6 MB
  float* out3 = (float*)alloc((size_t)MPAD * 128 * 4);                  // 10.3 MB
  unsigned short* xP = (unsigned short*)out3;  // alias: xP dead before out3 written
  unsigned short* wt1 = (unsigned short*)alloc((size_t)512 * 128 * 2);
  unsigned short* wt2 = (unsigned short*)alloc((size_t)512 * 512 * 2);
  unsigned short* wt3 = (unsigned short*)alloc((size_t)128 * 512 * 2);
  char* alStart = ws + off;
  float* alS1 = (float*)alloc((size_t)MPAD * 4 * 4);
  float* alD1 = (float*)alloc((size_t)MPAD * 4 * 4);
  float* alS2 = (float*)alloc((size_t)MPAD * 4 * 4);
  float* alD2 = (float*)alloc((size_t)MPAD * 4 * 4);
  float* alS3 = (float*)alloc((size_t)MPAD * 4);
  float* alD3 = (float*)alloc((size_t)MPAD * 4);
  int alcount = (int)(((ws + off) - alStart) / 4);
  int* deg = (int*)alloc((size_t)NN * 4);
  int* cursor = (int*)alloc((size_t)NN * 4);
  int* rowp = (int*)alloc((size_t)(NN + 1) * 4);
  int* colx = (int*)alloc((size_t)(NE + NN) * 4);
  unsigned* enc = (unsigned*)alloc((size_t)NBATCH * 128 * 4);
  int* flag = (int*)alloc(4);
  (void)ws_size; (void)n_in; (void)in_sizes; (void)out_size;

  k_init_prep<<<(PREPTOT + 255) / 256, 256, 0, stream>>>(
      W1, W2, W3, x, wt1, wt2, wt3, xP, deg, enc, flag, (float*)alStart, alcount);
  k_count<<<(NE + 255) / 256, 256, 0, stream>>>(ei, deg);
  k_scan<<<1, 1024, 0, stream>>>(deg, rowp, cursor);
  k_fill<<<(NE + NN + 255) / 256, 256, 0, stream>>>(ei, cursor, colx, nmask, flag);

  dim3 gg1(512 / BN, MPAD / 128);
  dim3 gg3(1, MPAD / 64);

  // Layer 1
  k_gemm<128, 256><<<gg1, 256, 0, stream>>>(xP, wt1, hA, as1, ad1, alS1, alD1,
                                            128, 512, 4);
  k_agg<4, true, true, true><<<NN, 256, 0, stream>>>(hA, alS1, alD1, rowp, colx,
                                                     b1, nullptr, hG);
  // Layer 2
  k_gemm<128, 256><<<gg1, 256, 0, stream>>>(hG, wt2, hA, as2, ad2, alS2, alD2,
                                            512, 512, 4);
  k_agg<4, true, true, true><<<NN, 256, 0, stream>>>(hA, alS2, alD2, rowp, colx,
                                                     b2, nullptr, hG);
  // Layer 3
  k_gemm<64, 128><<<gg3, 128, 0, stream>>>(hG, wt3, hA, as3, ad3, alS3, alD3,
                                           512, 128, 1);
  k_agg<1, false, false, false><<<(NN + 3) / 4, 256, 0, stream>>>(
      hA, alS3, alD3, rowp, colx, b3, out3, nullptr);

  // Masked global max pool
  k_pool<<<(NN + 31) / 32, 128, 0, stream>>>(out3, batch, nmask, flag, enc);
  k_out<<<(NBATCH * 128 + 255) / 256, 256, 0, stream>>>(enc, (float*)d_out);
}

// Round 17
// 347.147 us; speedup vs baseline: 1.1534x; 1.0030x over previous
//
#include <hip/hip_runtime.h>
#include <stdint.h>

// GAT encoder: 3 GAT layers + masked global max pool.
// fp16-storage pipeline (threshold 2% relative; r16 absmax 9.8e-4).
// r17: GEMM 1D-grid XCD-affinity swizzle (id%8 == bm%8 -> all 4 bn-blocks of
// one A row-block on one XCD; A fetched 1x not 4x), launch_bounds(.,4),
// MPAD 20480 (160 row-blocks = 8*20 for clean swizzle decode).

#define NN 20000
#define MPAD 20480
#define NE 320000
#define NBATCH 16
#define NEG 0.2f
#define WSCALE 64.0f
#define WINV 0.015625f

using f16x8 = __attribute__((ext_vector_type(8))) _Float16;
using f32x4 = __attribute__((ext_vector_type(4))) float;
using h2 = __attribute__((ext_vector_type(2))) _Float16;

#define GLL16(gp, lp)                                                        \
  __builtin_amdgcn_global_load_lds(                                          \
      (const __attribute__((address_space(1))) void*)(gp),                   \
      (__attribute__((address_space(3))) void*)(lp), 16, 0, 0)

static __device__ __forceinline__ unsigned short h2u(_Float16 h) {
  union { _Float16 f; unsigned short u; } c;
  c.f = h;
  return c.u;
}
static __device__ __forceinline__ h2 bits2h2(unsigned v) {
  union { unsigned u; h2 h; } c;
  c.u = v;
  return c.h;
}
static __device__ __forceinline__ unsigned h22bits(h2 h) {
  union { h2 h; unsigned u; } c;
  c.h = h;
  return c.u;
}
static __device__ __forceinline__ unsigned encf(float f) {
  unsigned u = __float_as_uint(f);
  return (u & 0x80000000u) ? ~u : (u | 0x80000000u);
}
static __device__ __forceinline__ float decf(unsigned u) {
  return __uint_as_float((u & 0x80000000u) ? (u ^ 0x80000000u) : ~u);
}

// -------- fused init+prep: deg/enc/flag/alpha-zero + W->fp16^T + x->fp16 ----
#define R1 (512 * 128)
#define R2 (512 * 512)
#define R3 (128 * 512)
#define PREPTOT (R1 + R2 + R3 + NN * 128)
__global__ void k_init_prep(const float* __restrict__ W1, const float* __restrict__ W2,
                            const float* __restrict__ W3, const float* __restrict__ x,
                            unsigned short* __restrict__ wt1,
                            unsigned short* __restrict__ wt2,
                            unsigned short* __restrict__ wt3,
                            unsigned short* __restrict__ xp, int* deg,
                            unsigned* enc, int* flag, float* alz, int alcount) {
  int idx = blockIdx.x * blockDim.x + threadIdx.x;
  if (idx < R1) {
    int n = idx & 511, k = idx >> 9;  // W1 [128][512]
    wt1[(size_t)n * 128 + k] = h2u((_Float16)(W1[(size_t)k * 512 + n] * WSCALE));
  } else if (idx < R1 + R2) {
    int j = idx - R1;
    int n = j & 511, k = j >> 9;  // W2 [512][512]
    wt2[(size_t)n * 512 + k] = h2u((_Float16)(W2[(size_t)k * 512 + n] * WSCALE));
  } else if (idx < R1 + R2 + R3) {
    int j = idx - (R1 + R2);
    int n = j & 127, k = j >> 7;  // W3 [512][128]
    wt3[(size_t)n * 512 + k] = h2u((_Float16)(W3[(size_t)k * 128 + n] * WSCALE));
  } else if (idx < PREPTOT) {
    int j = idx - (R1 + R2 + R3);
    xp[j] = h2u((_Float16)x[j]);
  }
  if (idx < NN) deg[idx] = 1;  // self loop
  if (idx < NBATCH * 128) enc[idx] = ~__float_as_uint(-1e30f);  // encf(-1e30)
  if (idx == 0) *flag = 0;
  if (idx < alcount) alz[idx] = 0.f;
}

__global__ void k_count(const int* __restrict__ ei, int* __restrict__ deg) {
  int e = blockIdx.x * blockDim.x + threadIdx.x;
  if (e < NE) atomicAdd(&deg[ei[NE + e]], 1);
}

__global__ void k_scan(const int* __restrict__ deg, int* __restrict__ row_ptr,
                       int* __restrict__ cursor) {
  __shared__ int wsum[16];
  int t = threadIdx.x;  // 1024 threads
  int lane = t & 63, wid = t >> 6;
  const int CH = 20;
  int beg = t * CH;
  int s = 0;
  for (int i = 0; i < CH; i++) {
    int idx = beg + i;
    if (idx < NN) s += deg[idx];
  }
  int incl = s;
  for (int off = 1; off < 64; off <<= 1) {
    int v = __shfl_up(incl, off, 64);
    if (lane >= off) incl += v;
  }
  if (lane == 63) wsum[wid] = incl;
  __syncthreads();
  if (t < 16) {
    int v = wsum[t];
    int in2 = v;
    for (int off = 1; off < 16; off <<= 1) {
      int u = __shfl_up(in2, off, 16);
      if (t >= off) in2 += u;
    }
    wsum[t] = in2 - v;  // exclusive wave base
  }
  __syncthreads();
  int run = wsum[wid] + incl - s;
  for (int i = 0; i < CH; i++) {
    int idx = beg + i;
    if (idx < NN) {
      row_ptr[idx] = run;
      cursor[idx] = run;
      run += deg[idx];
    }
  }
  if (t == 1023) row_ptr[NN] = run;
}

__global__ void k_fill(const int* __restrict__ ei, int* __restrict__ cursor,
                       int* __restrict__ col, const int* __restrict__ nmask,
                       int* __restrict__ flag) {
  int i = blockIdx.x * blockDim.x + threadIdx.x;
  if (i >= NE + NN) return;
  int src, dst;
  if (i < NE) {
    src = ei[i];
    dst = ei[NE + i];
  } else {
    src = dst = i - NE;
    if (nmask[src] != 0) *flag = 1;
  }
  int pos = atomicAdd(&cursor[dst], 1);
  col[pos] = src;
}

// ---------------- GEMM: fp16 x fp16 -> fp16 C, fp32 acc, alpha fused --------
// Swapped mfma operands: thread (lquad,lrow) reg r holds C[m=lrow][n=lquad*4+r].
// SWIZ: 1D grid, id%8 == (bm-block)%8 -> one XCD owns each A row-block (A
// fetched once into its L2; 4 bn-variants share it). Staging via
// global_load_lds width=16.
#define BN 128
#define BK 32

template <int BMT, int NT, bool SWIZ>
__global__ __launch_bounds__(NT, 4) void k_gemm(
    const unsigned short* __restrict__ Ap, const unsigned short* __restrict__ Wt,
    unsigned short* __restrict__ C, const float* __restrict__ attS,
    const float* __restrict__ attD, float* __restrict__ alS,
    float* __restrict__ alD, int K, int Nc, int H) {
  __shared__ __align__(16) unsigned short As[BMT][BK];
  __shared__ __align__(16) unsigned short Bs[BN][BK];
  int tid = threadIdx.x;
  int bm, bn;
  if constexpr (SWIZ) {
    int id = blockIdx.x;        // NBX=4: id = r + 8*(bn_i + 4*q), bm_row = q*8+r
    int r = id & 7, t = id >> 3;
    bn = (t & 3) * BN;
    bm = (((t >> 2) << 3) + r) * BMT;
  } else {
    bm = blockIdx.y * BMT;
    bn = blockIdx.x * BN;
  }
  int wid = tid >> 6, lane = tid & 63;
  int wm = (BMT == 128) ? (wid >> 1) * 64 : 0;
  int wn = (BMT == 128) ? (wid & 1) * 64 : wid * 64;
  int lrow = lane & 15, lquad = lane >> 4;

  f32x4 acc[4][4] = {};

  for (int k0 = 0; k0 < K; k0 += BK) {
    __syncthreads();
#pragma unroll
    for (int i = 0; i < (BMT * 4) / NT; i++) {
      int slot = tid + NT * i;
      int row = slot >> 2;
      int ks = (slot & 3) * 8;
      GLL16(Ap + (size_t)(bm + row) * K + k0 + ks, &As[0][0] + (size_t)slot * 8);
    }
#pragma unroll
    for (int i = 0; i < 512 / NT; i++) {
      int slot = tid + NT * i;
      int row = slot >> 2;
      int ks = (slot & 3) * 8;
      GLL16(Wt + (size_t)(bn + row) * K + k0 + ks, &Bs[0][0] + (size_t)slot * 8);
    }
    __syncthreads();

    f16x8 af[4];
#pragma unroll
    for (int mf = 0; mf < 4; mf++)
      af[mf] = *(const f16x8*)&As[wm + mf * 16 + lrow][lquad * 8];
#pragma unroll
    for (int nf = 0; nf < 4; nf++) {
      f16x8 bf = *(const f16x8*)&Bs[wn + nf * 16 + lrow][lquad * 8];
#pragma unroll
      for (int mf = 0; mf < 4; mf++)
        acc[mf][nf] =
            __builtin_amdgcn_mfma_f32_16x16x32_f16(bf, af[mf], acc[mf][nf], 0, 0, 0);
    }
  }
  // undo the x64 W scale
#pragma unroll
  for (int mf = 0; mf < 4; mf++)
#pragma unroll
    for (int nf = 0; nf < 4; nf++)
#pragma unroll
      for (int r = 0; r < 4; r++) acc[mf][nf][r] *= WINV;

  // fused alpha (this block's 128 cols == one head)
  float4 aS[4], aD[4];
#pragma unroll
  for (int nf = 0; nf < 4; nf++) {
    int n0 = bn + wn + nf * 16 + lquad * 4;
    aS[nf] = *(const float4*)(attS + n0);
    aD[nf] = *(const float4*)(attD + n0);
  }
  int head = bn >> 7;
#pragma unroll
  for (int mf = 0; mf < 4; mf++) {
    float ps = 0.f, pd = 0.f;
#pragma unroll
    for (int nf = 0; nf < 4; nf++) {
      ps += acc[mf][nf][0] * aS[nf].x + acc[mf][nf][1] * aS[nf].y +
            acc[mf][nf][2] * aS[nf].z + acc[mf][nf][3] * aS[nf].w;
      pd += acc[mf][nf][0] * aD[nf].x + acc[mf][nf][1] * aD[nf].y +
            acc[mf][nf][2] * aD[nf].z + acc[mf][nf][3] * aD[nf].w;
    }
    ps += __shfl_xor(ps, 16, 64);
    ps += __shfl_xor(ps, 32, 64);
    pd += __shfl_xor(pd, 16, 64);
    pd += __shfl_xor(pd, 32, 64);
    int row = bm + wm + mf * 16 + lrow;
    if (lquad == 0) {
      atomicAdd(&alS[(size_t)row * H + head], ps);
      atomicAdd(&alD[(size_t)row * H + head], pd);
    }
  }
  // C store: one 8B ushort4 per (mf,nf)
#pragma unroll
  for (int mf = 0; mf < 4; mf++) {
    int m = bm + wm + mf * 16 + lrow;
#pragma unroll
    for (int nf = 0; nf < 4; nf++) {
      int n0 = bn + wn + nf * 16 + lquad * 4;
      ushort4 o;
      o.x = h2u((_Float16)acc[mf][nf][0]);
      o.y = h2u((_Float16)acc[mf][nf][1]);
      o.z = h2u((_Float16)acc[mf][nf][2]);
      o.w = h2u((_Float16)acc[mf][nf][3]);
      *(ushort4*)(C + (size_t)m * Nc + n0) = o;
    }
  }
}

// ---------------- softmax + aggregate: 1 head/wave, half-wave edge pairs ----
// PIN=true (H=4): sub = blockIdx&3 -> head s on XCDs {s, s+4}.
// Fast path (deg<=64): t = exp(leaky(e) - leaky(adv)) packed UNNORMALIZED to
// LDS immediately (no max-reduce; sum-reduce overlaps gather issue); final
// scale by 1/S after the half merge. 8 gathers per half in flight.
template <int H, bool RELU, bool FP16OUT, bool PIN>
__global__ __launch_bounds__(256) void k_agg(
    const unsigned short* __restrict__ h, const float* __restrict__ as_,
    const float* __restrict__ ad_, const int* __restrict__ row_ptr,
    const int* __restrict__ col, const float* __restrict__ bias,
    float* __restrict__ out, unsigned short* __restrict__ outp) {
  constexpr int HF = H * 128;
  __shared__ unsigned long long cw[4][64];
  int tid = threadIdx.x, bwid = tid >> 6, lane = tid & 63;
  int node, sub;
  if constexpr (PIN) {
    sub = blockIdx.x & 3;
    node = (blockIdx.x >> 2) * 4 + bwid;  // grid = NN, NN%4==0
  } else {
    node = blockIdx.x * 4 + bwid;
    sub = 0;
    if (node >= NN) return;
  }
  int beg = row_ptr[node], end = row_ptr[node + 1];
  int deg = end - beg;
  float adv = ad_[(size_t)node * H + sub];
  float shift = (adv > 0.f) ? adv : NEG * adv;  // wave-uniform surrogate max
  float fscale = 1.f;
  bool fast = (deg <= 64);

  if (__builtin_expect(fast, 1)) {
    unsigned sidx = 0;
    float t = 0.f;
    if (lane < deg) {
      sidx = (unsigned)col[beg + lane];
      float e = as_[(size_t)sidx * H + sub] + adv;
      e = (e > 0.f) ? e : NEG * e;
      t = fminf(__expf(e - shift), 60000.f);  // f16-range guard
    }
    _Float16 ht = (_Float16)t;
    h2 hv;
    hv[0] = ht;
    hv[1] = ht;
    cw[bwid][lane] = ((unsigned long long)h22bits(hv) << 32) | sidx;
    float S = t;  // sum reduce; overlaps with phase-B gather issue
#pragma unroll
    for (int off = 32; off; off >>= 1) S += __shfl_xor(S, off, 64);
    fscale = 1.f / S;
  }
  float Mr = 0.f, Sinv = 0.f;
  if (!fast) {  // rare general path: normalized weights per chunk
    float m = -1e30f, s = 0.f;
    for (int j = beg + lane; j < end; j += 64) {
      int sidx = col[j];
      float e = as_[(size_t)sidx * H + sub] + adv;
      e = (e > 0.f) ? e : NEG * e;
      float nm = fmaxf(m, e);
      s = s * __expf(m - nm) + __expf(e - nm);
      m = nm;
    }
    float mm = m;
#pragma unroll
    for (int off = 32; off; off >>= 1) mm = fmaxf(mm, __shfl_xor(mm, off, 64));
    float t = s * __expf(m - mm);
#pragma unroll
    for (int off = 32; off; off >>= 1) t += __shfl_xor(t, off, 64);
    Mr = mm;
    Sinv = 1.f / t;
  }

  const int half = lane >> 5, hl = lane & 31;
  const int fbase = sub * 128 + hl * 4;  // 4 features/lane, 32 lanes = head row
  const int base = half * 8;
  float acc0 = 0.f, acc1 = 0.f, acc2 = 0.f, acc3 = 0.f;
  for (int c0 = beg; c0 < end; c0 += 64) {
    int cnt = min(64, end - c0);
    if (!fast) {  // refill normalized weights; zero-pad all 64 slots
      unsigned sidx = 0;
      float w = 0.f;
      if (lane < cnt) {
        sidx = (unsigned)col[c0 + lane];
        float e = as_[(size_t)sidx * H + sub] + adv;
        e = (e > 0.f) ? e : NEG * e;
        w = __expf(e - Mr) * Sinv;
      }
      _Float16 hw = (_Float16)w;
      h2 hv;
      hv[0] = hw;
      hv[1] = hw;
      cw[bwid][lane] = ((unsigned long long)h22bits(hv) << 32) | sidx;
    }
    h2 hacc0 = {(_Float16)0.f, (_Float16)0.f};
    h2 hacc1 = {(_Float16)0.f, (_Float16)0.f};
    for (int je = 0; je < cnt; je += 16) {  // 16 edges/iter (8 per half)
      unsigned long long q[8];
#pragma unroll
      for (int r = 0; r < 8; r++) q[r] = cw[bwid][je + base + r];
      uint2 v[8];
#pragma unroll
      for (int r = 0; r < 8; r++)
        v[r] = *(const uint2*)(h + (size_t)(unsigned)q[r] * HF + fbase);
#pragma unroll
      for (int r = 0; r < 8; r++) {
        h2 hw = bits2h2((unsigned)(q[r] >> 32));
        hacc0 += hw * bits2h2(v[r].x);
        hacc1 += hw * bits2h2(v[r].y);
      }
    }
    acc0 += (float)hacc0[0];
    acc1 += (float)hacc0[1];
    acc2 += (float)hacc1[0];
    acc3 += (float)hacc1[1];
  }
  // merge the two halves, then apply deferred normalization
  acc0 += __shfl_xor(acc0, 32, 64);
  acc1 += __shfl_xor(acc1, 32, 64);
  acc2 += __shfl_xor(acc2, 32, 64);
  acc3 += __shfl_xor(acc3, 32, 64);
  if (half == 0) {
    float4 b = *(const float4*)(bias + fbase);
    float v0 = acc0 * fscale + b.x, v1 = acc1 * fscale + b.y;
    float v2 = acc2 * fscale + b.z, v3 = acc3 * fscale + b.w;
    if (RELU) {
      v0 = fmaxf(v0, 0.f);
      v1 = fmaxf(v1, 0.f);
      v2 = fmaxf(v2, 0.f);
      v3 = fmaxf(v3, 0.f);
    }
    if constexpr (FP16OUT) {
      ushort4 o;
      o.x = h2u((_Float16)v0);
      o.y = h2u((_Float16)v1);
      o.z = h2u((_Float16)v2);
      o.w = h2u((_Float16)v3);
      *(ushort4*)(outp + (size_t)node * HF + fbase) = o;
    } else {
      float4 o = make_float4(v0, v1, v2, v3);
      *(float4*)(out + (size_t)node * HF + fbase) = o;
    }
  }
}

// ---------------- masked global max pool ----------------
__global__ void k_pool(const float* __restrict__ h, const int* __restrict__ batch,
                       const int* __restrict__ mask, const int* __restrict__ flag,
                       unsigned* __restrict__ enc) {
  int f = threadIdx.x;  // 128 threads = 128 features
  int n0 = blockIdx.x * 32;
  if (n0 >= NN) return;
  int n1 = min(NN, n0 + 32);
  int any = *flag;
  float local = -1e30f;
  int curb = batch[n0];
  for (int n = n0; n < n1; ++n) {
    int b = batch[n];
    if (b != curb) {
      if (local > -1e30f) atomicMax(&enc[curb * 128 + f], encf(local));
      local = -1e30f;
      curb = b;
    }
    bool valid = (mask[n] == 0) || (!any);
    if (valid) local = fmaxf(local, h[(size_t)n * 128 + f]);
  }
  if (local > -1e30f) atomicMax(&enc[curb * 128 + f], encf(local));
}

__global__ void k_out(const unsigned* __restrict__ enc, float* __restrict__ out) {
  int i = blockIdx.x * blockDim.x + threadIdx.x;
  if (i < NBATCH * 128) out[i] = decf(enc[i]);
}

extern "C" void kernel_launch(void* const* d_in, const int* in_sizes, int n_in,
                              void* d_out, int out_size, void* d_ws, size_t ws_size,
                              hipStream_t stream) {
  const float* x = (const float*)d_in[0];
  const int* ei = (const int*)d_in[1];
  const int* batch = (const int*)d_in[2];
  const int* nmask = (const int*)d_in[3];
  // d_in[4] = edge_mask, unused
  const float* W1 = (const float*)d_in[5];
  const float* as1 = (const float*)d_in[6];
  const float* ad1 = (const float*)d_in[7];
  const float* b1 = (const float*)d_in[8];
  const float* W2 = (const float*)d_in[9];
  const float* as2 = (const float*)d_in[10];
  const float* ad2 = (const float*)d_in[11];
  const float* b2 = (const float*)d_in[12];
  const float* W3 = (const float*)d_in[13];
  const float* as3 = (const float*)d_in[14];
  const float* ad3 = (const float*)d_in[15];
  const float* b3 = (const float*)d_in[16];

  char* ws = (char*)d_ws;
  size_t off = 0;
  auto alloc = [&](size_t bytes) -> char* {
    char* p = ws + off;
    off = (off + bytes + 255) & ~(size_t)255;
    return p;
  };
  unsigned short* hA = (unsigned short*)alloc((size_t)MPAD * 512 * 2);  // 21 MB
  unsigned short* hG = (unsigned short*)alloc((size_t)MPAD * 512 * 2);  // 21 MB
  float* out3 = (float*)alloc((size_t)MPAD * 128 * 4);                  // 10.5 MB
  unsigned short* xP = (unsigned short*)out3;  // alias: xP dead before out3 written
  unsigned short* wt1 = (unsigned short*)alloc((size_t)512 * 128 * 2);
  unsigned short* wt2 = (unsigned short*)alloc((size_t)512 * 512 * 2);
  unsigned short* wt3 = (unsigned short*)alloc((size_t)128 * 512 * 2);
  char* alStart = ws + off;
  float* alS1 = (float*)alloc((size_t)MPAD * 4 * 4);
  float* alD1 = (float*)alloc((size_t)MPAD * 4 * 4);
  float* alS2 = (float*)alloc((size_t)MPAD * 4 * 4);
  float* alD2 = (float*)alloc((size_t)MPAD * 4 * 4);
  float* alS3 = (float*)alloc((size_t)MPAD * 4);
  float* alD3 = (float*)alloc((size_t)MPAD * 4);
  int alcount = (int)(((ws + off) - alStart) / 4);
  int* deg = (int*)alloc((size_t)NN * 4);
  int* cursor = (int*)alloc((size_t)NN * 4);
  int* rowp = (int*)alloc((size_t)(NN + 1) * 4);
  int* colx = (int*)alloc((size_t)(NE + NN) * 4);
  unsigned* enc = (unsigned*)alloc((size_t)NBATCH * 128 * 4);
  int* flag = (int*)alloc(4);
  (void)ws_size; (void)n_in; (void)in_sizes; (void)out_size;

  k_init_prep<<<(PREPTOT + 255) / 256, 256, 0, stream>>>(
      W1, W2, W3, x, wt1, wt2, wt3, xP, deg, enc, flag, (float*)alStart, alcount);
  k_count<<<(NE + 255) / 256, 256, 0, stream>>>(ei, deg);
  k_scan<<<1, 1024, 0, stream>>>(deg, rowp, cursor);
  k_fill<<<(NE + NN + 255) / 256, 256, 0, stream>>>(ei, cursor, colx, nmask, flag);

  const int gemmBlocks = 4 * (MPAD / 128);  // 640, 1D swizzled
  dim3 gg3(1, MPAD / 64);

  // Layer 1
  k_gemm<128, 256, true><<<gemmBlocks, 256, 0, stream>>>(
      xP, wt1, hA, as1, ad1, alS1, alD1, 128, 512, 4);
  k_agg<4, true, true, true><<<NN, 256, 0, stream>>>(hA, alS1, alD1, rowp, colx,
                                                     b1, nullptr, hG);
  // Layer 2
  k_gemm<128, 256, true><<<gemmBlocks, 256, 0, stream>>>(
      hG, wt2, hA, as2, ad2, alS2, alD2, 512, 512, 4);
  k_agg<4, true, true, true><<<NN, 256, 0, stream>>>(hA, alS2, alD2, rowp, colx,
                                                     b2, nullptr, hG);
  // Layer 3
  k_gemm<64, 128, false><<<gg3, 128, 0, stream>>>(hG, wt3, hA, as3, ad3, alS3,
                                                  alD3, 512, 128, 1);
  k_agg<1, false, false, false><<<(NN + 3) / 4, 256, 0, stream>>>(
      hA, alS3, alD3, rowp, colx, b3, out3, nullptr);

  // Masked global max pool
  k_pool<<<(NN + 31) / 32, 128, 0, stream>>>(out3, batch, nmask, flag, enc);
  k_out<<<(NBATCH * 128 + 255) / 256, 256, 0, stream>>>(enc, (float*)d_out);
}